// Round 5
// baseline (319.306 us; speedup 1.0000x reference)
//
#include <hip/hip_runtime.h>

#define NB 256
#define NM 128
#define ND 64
#define NH 8

typedef float f32x4 __attribute__((ext_vector_type(4)));
typedef short bf16x8 __attribute__((ext_vector_type(8)));   // 8 bf16 = 4 VGPRs
typedef unsigned short ushort_t;

__device__ __forceinline__ ushort_t f2bf(float f) {   // RNE f32->bf16
    unsigned int x = __float_as_uint(f);
    x += 0x7fffu + ((x >> 16) & 1u);
    return (ushort_t)(x >> 16);
}

// XOR-swizzled LDS indices (T2): col ^= 8*(row&7). Applied on BOTH write and read.
__device__ __forceinline__ int sw64(int row, int col)  { return row * 64  + (col ^ ((row & 7) << 3)); }
__device__ __forceinline__ int sw128(int row, int col) { return row * 128 + (col ^ ((row & 7) << 3)); }

__device__ __forceinline__ f32x4 MFMA(bf16x8 a, bf16x8 b, f32x4 c) {
    return __builtin_amdgcn_mfma_f32_16x16x32_bf16(a, b, c, 0, 0, 0);
}

// ---- prep: transpose weights to bf16 fragment-friendly layout in d_ws ----
// ws (ushort): WqT[512][64] @0, WkT @32768, WvT @65536, WpT[64][512] @98304  (256 KB)
extern "C" __global__ void geat_prep(const float* __restrict__ Wq,
                                     const float* __restrict__ Wk,
                                     const float* __restrict__ Wv,
                                     const float* __restrict__ Wp,
                                     ushort_t* __restrict__ ws)
{
    int idx = blockIdx.x * 256 + threadIdx.x;   // 0..131071
    int seg = idx >> 15;
    int r = idx & 32767;
    float v;
    if      (seg == 0) v = Wq[(r & 63) * 512 + (r >> 6)];    // WqT[o][d] = Wq[d][o]
    else if (seg == 1) v = Wk[(r & 63) * 512 + (r >> 6)];
    else if (seg == 2) v = Wv[(r & 63) * 512 + (r >> 6)];
    else               v = Wp[(r & 511) * 64 + (r >> 9)];    // WpT[c][k] = Wp[k][c]
    ws[idx] = f2bf(v);
}

// LDS = 80 KB exactly -> 2 blocks/CU (160 KB). launch_bounds(512,4) = 4 waves/EU
// = 2 blocks/CU, caps VGPR at 128 (the natural count; statically-indexed frags only).
extern "C" __global__ __launch_bounds__(512, 4)
void geat_mfma(const float* __restrict__ x, const int* __restrict__ edges,
               const float* __restrict__ bq, const float* __restrict__ bk,
               const float* __restrict__ bv, const float* __restrict__ ebias,
               const float* __restrict__ bp, const ushort_t* __restrict__ wt,
               float* __restrict__ out)
{
    __shared__ __align__(16) ushort_t sm[40960];   // 80 KB bf16: QB,KB,VT,PB
    ushort_t* QB  = sm;                 // Q    [128][64] (reused for O tiles; wave-private rows)
    ushort_t* KB  = sm + 8192;          // K    [128][64]
    ushort_t* VTB = sm + 16384;         // V^T  [64][128]
    ushort_t* PB  = sm + 24576;         // P    [128][128] (wave-private rows)

    const int b    = blockIdx.x;
    const int tid  = threadIdx.x;
    const int w    = tid >> 6;          // wave 0..7
    const int lane = tid & 63;
    const int c    = lane & 15;         // fragment row/col index
    const int g    = lane >> 4;         // k-chunk group 0..3
    const int mt   = w * 16;            // wave's output rows

    const ushort_t* WqT = wt;
    const ushort_t* WkT = wt + 32768;
    const ushort_t* WvT = wt + 65536;
    const ushort_t* WpT = wt + 98304;

    // ---- x A-frags straight from global into registers (head-invariant) ----
    // lane holds x[mt+c][kt*32 + 8g .. +7]; also serves as x^T B-frag for V^T.
    bf16x8 xA[2];
    {
        const float* xb = x + (size_t)b * NM * ND + (mt + c) * ND;
#pragma unroll
        for (int kt = 0; kt < 2; ++kt) {
            const float4 lo = *(const float4*)&xb[kt * 32 + 8 * g];
            const float4 hi = *(const float4*)&xb[kt * 32 + 8 * g + 4];
            bf16x8 f;
            f[0] = f2bf(lo.x); f[1] = f2bf(lo.y); f[2] = f2bf(lo.z); f[3] = f2bf(lo.w);
            f[4] = f2bf(hi.x); f[5] = f2bf(hi.y); f[6] = f2bf(hi.z); f[7] = f2bf(hi.w);
            xA[kt] = f;
        }
    }

    // ---- cache edge codes for this wave's S fragments (head-invariant) ----
    // element (m = mt+4g+r, n = nt*16+c); values 0..4 packed 4x8b per nt
    unsigned epack[8];
    {
        const int* eg = edges + (size_t)b * NM * NM;
#pragma unroll
        for (int nt = 0; nt < 8; ++nt) {
            unsigned pk = 0;
#pragma unroll
            for (int r = 0; r < 4; ++r)
                pk |= ((unsigned)eg[(mt + 4 * g + r) * NM + nt * 16 + c] & 0xffu) << (8 * r);
            epack[nt] = pk;
        }
    }

    f32x4 projacc[4];
#pragma unroll
    for (int i = 0; i < 4; ++i) projacc[i] = (f32x4)0.0f;

    // no initial barrier: first cross-wave LDS reads are after barrier 1

#pragma unroll 1
    for (int h = 0; h < NH; ++h) {
        // ================= Phase A: Q, K, V^T projections =================
#pragma unroll
        for (int nt4 = 0; nt4 < 4; ++nt4) {
            int n0 = nt4 * 16;
            float bqv = bq[h * 64 + n0 + c];
            float bkv = bk[h * 64 + n0 + c];
            f32x4 qacc = {bqv, bqv, bqv, bqv};   // bias depends on col only
            f32x4 kacc = {bkv, bkv, bkv, bkv};
#pragma unroll
            for (int kt = 0; kt < 2; ++kt) {
                const bf16x8 wq = *(const bf16x8*)&WqT[(h * 64 + n0 + c) * 64 + kt * 32 + 8 * g];
                const bf16x8 wk = *(const bf16x8*)&WkT[(h * 64 + n0 + c) * 64 + kt * 32 + 8 * g];
                qacc = MFMA(xA[kt], wq, qacc);
                kacc = MFMA(xA[kt], wk, kacc);
            }
#pragma unroll
            for (int r = 0; r < 4; ++r) {        // D-frag: row=mt+4g+r, col=n0+c
                QB[sw64(mt + 4 * g + r, n0 + c)] = f2bf(qacc[r]);
                KB[sw64(mt + 4 * g + r, n0 + c)] = f2bf(kacc[r]);
            }
        }
        // V^T = WvT · x^T : wave w computes V^T cols mt..mt+15, all 64 d-rows
#pragma unroll
        for (int dt = 0; dt < 4; ++dt) {
            int d0 = dt * 16;
            f32x4 vacc;
#pragma unroll
            for (int r = 0; r < 4; ++r) vacc[r] = bv[h * 64 + d0 + 4 * g + r];  // bias on d (row)
#pragma unroll
            for (int kt = 0; kt < 2; ++kt) {
                const bf16x8 wv = *(const bf16x8*)&WvT[(h * 64 + d0 + c) * 64 + kt * 32 + 8 * g];
                vacc = MFMA(wv, xA[kt], vacc);   // A = WvT rows (d), B = x^T cols (n=mt+c)
            }
#pragma unroll
            for (int r = 0; r < 4; ++r)
                VTB[sw128(d0 + 4 * g + r, mt + c)] = f2bf(vacc[r]);
        }
        __syncthreads();   // barrier 1: KB / VTB now visible to all waves

        // ================= Phase B: S = QK^T/8 + bias, leaky, mask, softmax, P =================
        bf16x8 qA[2];
#pragma unroll
        for (int kt = 0; kt < 2; ++kt)
            qA[kt] = *(const bf16x8*)&QB[sw64(mt + c, kt * 32 + 8 * g)];

        float eb0 = ebias[0 * NH + h], eb1 = ebias[1 * NH + h], eb2 = ebias[2 * NH + h];
        float eb3 = ebias[3 * NH + h], eb4 = ebias[4 * NH + h];

        f32x4 s[8];
#pragma unroll
        for (int nt = 0; nt < 8; ++nt) {
            int n0 = nt * 16;
            f32x4 acc = (f32x4)0.0f;
#pragma unroll
            for (int kt = 0; kt < 2; ++kt) {
                const bf16x8 kf = *(const bf16x8*)&KB[sw64(n0 + c, kt * 32 + 8 * g)];
                acc = MFMA(qA[kt], kf, acc);
            }
#pragma unroll
            for (int r = 0; r < 4; ++r) {
                int e = (epack[nt] >> (8 * r)) & 0xff;
                float bias = (e == 1) ? eb1 : (e == 2) ? eb2 : (e == 3) ? eb3 : (e == 4) ? eb4 : eb0;
                float sv = acc[r] * 0.125f + bias;
                sv = (sv > 0.f) ? sv : 0.2f * sv;        // leaky BEFORE mask (ref order)
                acc[r] = (e > 0) ? sv : -1e9f;
            }
            s[nt] = acc;
        }
        // softmax per row (row = mt+4g+r): per-lane partial over nt, then 16-lane butterfly
        f32x4 mx;
#pragma unroll
        for (int r = 0; r < 4; ++r) {
            float m0 = s[0][r];
#pragma unroll
            for (int nt = 1; nt < 8; ++nt) m0 = fmaxf(m0, s[nt][r]);
            mx[r] = m0;
        }
#pragma unroll
        for (int d = 1; d < 16; d <<= 1)
#pragma unroll
            for (int r = 0; r < 4; ++r) mx[r] = fmaxf(mx[r], __shfl_xor(mx[r], d));
        f32x4 sum = (f32x4)0.0f;
#pragma unroll
        for (int nt = 0; nt < 8; ++nt)
#pragma unroll
            for (int r = 0; r < 4; ++r) {
                float ev = __expf(s[nt][r] - mx[r]);
                s[nt][r] = ev;
                sum[r] += ev;
            }
#pragma unroll
        for (int d = 1; d < 16; d <<= 1)
#pragma unroll
            for (int r = 0; r < 4; ++r) sum[r] += __shfl_xor(sum[r], d);
        f32x4 inv;
#pragma unroll
        for (int r = 0; r < 4; ++r) inv[r] = 1.f / sum[r];
#pragma unroll
        for (int nt = 0; nt < 8; ++nt)
#pragma unroll
            for (int r = 0; r < 4; ++r)
                PB[sw128(mt + 4 * g + r, nt * 16 + c)] = f2bf(s[nt][r] * inv[r]);
        // P rows are wave-private (written & read only by wave w) -> no barrier

        // ================= Phase C: O = P·V, then out-proj accumulate =================
        bf16x8 pA[4];
#pragma unroll
        for (int kt = 0; kt < 4; ++kt)
            pA[kt] = *(const bf16x8*)&PB[sw128(mt + c, kt * 32 + 8 * g)];
#pragma unroll
        for (int dt = 0; dt < 4; ++dt) {
            int d0 = dt * 16;
            f32x4 oacc = (f32x4)0.0f;
#pragma unroll
            for (int kt = 0; kt < 4; ++kt) {
                const bf16x8 vf = *(const bf16x8*)&VTB[sw128(d0 + c, kt * 32 + 8 * g)];
                oacc = MFMA(pA[kt], vf, oacc);   // B-frag: V[k][d0+c] = VT[d0+c][k]
            }
#pragma unroll
            for (int r = 0; r < 4; ++r)          // O tile -> QB own rows (Q is dead)
                QB[sw64(mt + 4 * g + r, d0 + c)] = f2bf(oacc[r]);
        }
        bf16x8 oA[2];
#pragma unroll
        for (int kt = 0; kt < 2; ++kt)
            oA[kt] = *(const bf16x8*)&QB[sw64(mt + c, kt * 32 + 8 * g)];
#pragma unroll
        for (int nt4 = 0; nt4 < 4; ++nt4) {
            int n0 = nt4 * 16;
#pragma unroll
            for (int kt = 0; kt < 2; ++kt) {
                const bf16x8 wp = *(const bf16x8*)&WpT[(n0 + c) * 512 + h * 64 + kt * 32 + 8 * g];
                projacc[nt4] = MFMA(oA[kt], wp, projacc[nt4]);
            }
        }
        __syncthreads();   // barrier 2: before next head overwrites KB/VTB
    }

    // ---- epilogue: + bp, coalesced f32 stores ----
    {
        float* og = out + (size_t)b * NM * ND;
#pragma unroll
        for (int nt4 = 0; nt4 < 4; ++nt4) {
            int n0 = nt4 * 16;
            float bpv = bp[n0 + c];
#pragma unroll
            for (int r = 0; r < 4; ++r)
                og[(mt + 4 * g + r) * ND + n0 + c] = projacc[nt4][r] + bpv;
        }
    }
}

extern "C" void kernel_launch(void* const* d_in, const int* in_sizes, int n_in,
                              void* d_out, int out_size, void* d_ws, size_t ws_size,
                              hipStream_t stream) {
    const float* x     = (const float*)d_in[0];
    const int*   edges = (const int*)d_in[1];
    const float* Wq    = (const float*)d_in[2];
    const float* bq    = (const float*)d_in[3];
    const float* Wk    = (const float*)d_in[4];
    const float* bk    = (const float*)d_in[5];
    const float* Wv    = (const float*)d_in[6];
    const float* bv    = (const float*)d_in[7];
    const float* eb    = (const float*)d_in[8];
    const float* Wp    = (const float*)d_in[9];
    const float* bp    = (const float*)d_in[10];
    float* out = (float*)d_out;
    ushort_t* ws = (ushort_t*)d_ws;   // needs 262144 B

    hipLaunchKernelGGL(geat_prep, dim3(512), dim3(256), 0, stream, Wq, Wk, Wv, Wp, ws);
    hipLaunchKernelGGL(geat_mfma, dim3(NB), dim3(512), 0, stream,
                       x, edges, bq, bk, bv, eb, bp, ws, out);
}

// Round 6
// 133.841 us; speedup vs baseline: 2.3857x; 2.3857x over previous
//
#include <hip/hip_runtime.h>

#define NB 256
#define NM 128
#define ND 64
#define NH 8

typedef float f32x4 __attribute__((ext_vector_type(4)));
typedef short bf16x8 __attribute__((ext_vector_type(8)));   // 8 bf16 = 4 VGPRs
typedef unsigned short ushort_t;

__device__ __forceinline__ ushort_t f2bf(float f) {   // RNE f32->bf16
    unsigned int x = __float_as_uint(f);
    x += 0x7fffu + ((x >> 16) & 1u);
    return (ushort_t)(x >> 16);
}

// XOR-swizzled LDS indices (T2): col ^= 8*(row&7). Applied on BOTH write and read.
__device__ __forceinline__ int sw64(int row, int col)  { return row * 64  + (col ^ ((row & 7) << 3)); }
__device__ __forceinline__ int sw128(int row, int col) { return row * 128 + (col ^ ((row & 7) << 3)); }

__device__ __forceinline__ f32x4 MFMA(bf16x8 a, bf16x8 b, f32x4 c) {
    return __builtin_amdgcn_mfma_f32_16x16x32_bf16(a, b, c, 0, 0, 0);
}

// ---- prep: transpose weights to bf16 fragment-friendly layout in d_ws ----
// ws (ushort): WqT[512][64] @0, WkT @32768, WvT @65536, WpT[64][512] @98304  (256 KB)
extern "C" __global__ void geat_prep(const float* __restrict__ Wq,
                                     const float* __restrict__ Wk,
                                     const float* __restrict__ Wv,
                                     const float* __restrict__ Wp,
                                     ushort_t* __restrict__ ws)
{
    int idx = blockIdx.x * 256 + threadIdx.x;   // 0..131071
    int seg = idx >> 15;
    int r = idx & 32767;
    float v;
    if      (seg == 0) v = Wq[(r & 63) * 512 + (r >> 6)];    // WqT[o][d] = Wq[d][o]
    else if (seg == 1) v = Wk[(r & 63) * 512 + (r >> 6)];
    else if (seg == 2) v = Wv[(r & 63) * 512 + (r >> 6)];
    else               v = Wp[(r & 511) * 64 + (r >> 9)];    // WpT[c][k] = Wp[k][c]
    ws[idx] = f2bf(v);
}

// LDS = 64 KB -> 2 blocks/CU (128 KB of 160, with slack). VGPR target: natural 128
// (=> 16 waves/CU register ceiling). DO NOT pass a min-waves hint: the compiler's
// budget model is 256/min_waves VGPRs ((512,2)->128 r2, (512,4)->64 r5 -> spills).
extern "C" __global__ __launch_bounds__(512, 1)
void geat_mfma(const float* __restrict__ x, const int* __restrict__ edges,
               const float* __restrict__ bq, const float* __restrict__ bk,
               const float* __restrict__ bv, const float* __restrict__ ebias,
               const float* __restrict__ bp, const ushort_t* __restrict__ wt,
               float* __restrict__ out)
{
    __shared__ __align__(16) ushort_t sm[32768];   // 64 KB bf16: QB,KB,VTB,PB(half)
    ushort_t* QB  = sm;                 // Q    [128][64] (reused for O; wave-private rows)
    ushort_t* KB  = sm + 8192;          // K    [128][64]
    ushort_t* VTB = sm + 16384;         // V^T  [64][128]
    ushort_t* PB  = sm + 24576;         // P half [128][64] (wave-private rows, 2 passes)

    const int b    = blockIdx.x;
    const int tid  = threadIdx.x;
    const int w    = tid >> 6;          // wave 0..7
    const int lane = tid & 63;
    const int c    = lane & 15;         // fragment row/col index
    const int g    = lane >> 4;         // k-chunk group 0..3
    const int mt   = w * 16;            // wave's output rows

    const ushort_t* WqT = wt;
    const ushort_t* WkT = wt + 32768;
    const ushort_t* WvT = wt + 65536;
    const ushort_t* WpT = wt + 98304;

    // ---- x A-frags straight from global into registers (head-invariant) ----
    // lane holds x[mt+c][kt*32 + 8g .. +7]; also serves as x^T B-frag for V^T.
    bf16x8 xA[2];
    {
        const float* xb = x + (size_t)b * NM * ND + (mt + c) * ND;
#pragma unroll
        for (int kt = 0; kt < 2; ++kt) {
            const float4 lo = *(const float4*)&xb[kt * 32 + 8 * g];
            const float4 hi = *(const float4*)&xb[kt * 32 + 8 * g + 4];
            bf16x8 f;
            f[0] = f2bf(lo.x); f[1] = f2bf(lo.y); f[2] = f2bf(lo.z); f[3] = f2bf(lo.w);
            f[4] = f2bf(hi.x); f[5] = f2bf(hi.y); f[6] = f2bf(hi.z); f[7] = f2bf(hi.w);
            xA[kt] = f;
        }
    }

    // ---- cache edge codes for this wave's S fragments (head-invariant) ----
    // element (m = mt+4g+r, n = nt*16+c); values 0..4 packed 4x8b per nt
    unsigned epack[8];
    {
        const int* eg = edges + (size_t)b * NM * NM;
#pragma unroll
        for (int nt = 0; nt < 8; ++nt) {
            unsigned pk = 0;
#pragma unroll
            for (int r = 0; r < 4; ++r)
                pk |= ((unsigned)eg[(mt + 4 * g + r) * NM + nt * 16 + c] & 0xffu) << (8 * r);
            epack[nt] = pk;
        }
    }

    f32x4 projacc[4];
#pragma unroll
    for (int i = 0; i < 4; ++i) projacc[i] = (f32x4)0.0f;

    // no initial barrier: first cross-wave LDS reads are after barrier 1

#pragma unroll 1
    for (int h = 0; h < NH; ++h) {
        // ================= Phase A: Q, K, V^T projections =================
#pragma unroll
        for (int nt4 = 0; nt4 < 4; ++nt4) {
            int n0 = nt4 * 16;
            float bqv = bq[h * 64 + n0 + c];
            float bkv = bk[h * 64 + n0 + c];
            f32x4 qacc = {bqv, bqv, bqv, bqv};   // bias depends on col only
            f32x4 kacc = {bkv, bkv, bkv, bkv};
#pragma unroll
            for (int kt = 0; kt < 2; ++kt) {
                const bf16x8 wq = *(const bf16x8*)&WqT[(h * 64 + n0 + c) * 64 + kt * 32 + 8 * g];
                const bf16x8 wk = *(const bf16x8*)&WkT[(h * 64 + n0 + c) * 64 + kt * 32 + 8 * g];
                qacc = MFMA(xA[kt], wq, qacc);
                kacc = MFMA(xA[kt], wk, kacc);
            }
#pragma unroll
            for (int r = 0; r < 4; ++r) {        // D-frag: row=mt+4g+r, col=n0+c
                QB[sw64(mt + 4 * g + r, n0 + c)] = f2bf(qacc[r]);
                KB[sw64(mt + 4 * g + r, n0 + c)] = f2bf(kacc[r]);
            }
        }
        // V^T = WvT · x^T : wave w computes V^T cols mt..mt+15, all 64 d-rows
#pragma unroll
        for (int dt = 0; dt < 4; ++dt) {
            int d0 = dt * 16;
            f32x4 vacc;
#pragma unroll
            for (int r = 0; r < 4; ++r) vacc[r] = bv[h * 64 + d0 + 4 * g + r];  // bias on d (row)
#pragma unroll
            for (int kt = 0; kt < 2; ++kt) {
                const bf16x8 wv = *(const bf16x8*)&WvT[(h * 64 + d0 + c) * 64 + kt * 32 + 8 * g];
                vacc = MFMA(wv, xA[kt], vacc);   // A = WvT rows (d), B = x^T cols (n=mt+c)
            }
#pragma unroll
            for (int r = 0; r < 4; ++r)
                VTB[sw128(d0 + 4 * g + r, mt + c)] = f2bf(vacc[r]);
        }
        __syncthreads();   // barrier 1: KB / VTB now visible to all waves

        // ================= Phase B: S = QK^T/8 + bias, leaky, mask, softmax =================
        bf16x8 qA[2];
#pragma unroll
        for (int kt = 0; kt < 2; ++kt)
            qA[kt] = *(const bf16x8*)&QB[sw64(mt + c, kt * 32 + 8 * g)];

        float eb0 = ebias[0 * NH + h], eb1 = ebias[1 * NH + h], eb2 = ebias[2 * NH + h];
        float eb3 = ebias[3 * NH + h], eb4 = ebias[4 * NH + h];

        f32x4 s[8];
#pragma unroll
        for (int nt = 0; nt < 8; ++nt) {
            int n0 = nt * 16;
            f32x4 acc = (f32x4)0.0f;
#pragma unroll
            for (int kt = 0; kt < 2; ++kt) {
                const bf16x8 kf = *(const bf16x8*)&KB[sw64(n0 + c, kt * 32 + 8 * g)];
                acc = MFMA(qA[kt], kf, acc);
            }
#pragma unroll
            for (int r = 0; r < 4; ++r) {
                int e = (epack[nt] >> (8 * r)) & 0xff;
                float bias = (e == 1) ? eb1 : (e == 2) ? eb2 : (e == 3) ? eb3 : (e == 4) ? eb4 : eb0;
                float sv = acc[r] * 0.125f + bias;
                sv = (sv > 0.f) ? sv : 0.2f * sv;        // leaky BEFORE mask (ref order)
                acc[r] = (e > 0) ? sv : -1e9f;
            }
            s[nt] = acc;
        }
        // softmax per row (row = mt+4g+r): per-lane partial over nt, then 16-lane butterfly
        f32x4 mx;
#pragma unroll
        for (int r = 0; r < 4; ++r) {
            float m0 = s[0][r];
#pragma unroll
            for (int nt = 1; nt < 8; ++nt) m0 = fmaxf(m0, s[nt][r]);
            mx[r] = m0;
        }
#pragma unroll
        for (int d = 1; d < 16; d <<= 1)
#pragma unroll
            for (int r = 0; r < 4; ++r) mx[r] = fmaxf(mx[r], __shfl_xor(mx[r], d));
        f32x4 sum = (f32x4)0.0f;
#pragma unroll
        for (int nt = 0; nt < 8; ++nt)
#pragma unroll
            for (int r = 0; r < 4; ++r) {
                float ev = __expf(s[nt][r] - mx[r]);
                s[nt][r] = ev;
                sum[r] += ev;
            }
#pragma unroll
        for (int d = 1; d < 16; d <<= 1)
#pragma unroll
            for (int r = 0; r < 4; ++r) sum[r] += __shfl_xor(sum[r], d);
        f32x4 inv;
#pragma unroll
        for (int r = 0; r < 4; ++r) inv[r] = 1.f / sum[r];

        // ================= Phase C: O = P·V in two half-passes over PB[128][64] =================
        // P rows are wave-private -> no barrier around the PB reuse.
        f32x4 oacc[4];
#pragma unroll
        for (int dt = 0; dt < 4; ++dt) oacc[dt] = (f32x4)0.0f;

#pragma unroll
        for (int half = 0; half < 2; ++half) {
#pragma unroll
            for (int nt = 0; nt < 4; ++nt)       // global nt' = half*4 + nt
#pragma unroll
                for (int r = 0; r < 4; ++r)
                    PB[sw64(mt + 4 * g + r, nt * 16 + c)] = f2bf(s[half * 4 + nt][r] * inv[r]);
            bf16x8 pA[2];
#pragma unroll
            for (int kt = 0; kt < 2; ++kt)
                pA[kt] = *(const bf16x8*)&PB[sw64(mt + c, kt * 32 + 8 * g)];
#pragma unroll
            for (int dt = 0; dt < 4; ++dt) {
                int d0 = dt * 16;
#pragma unroll
                for (int kt = 0; kt < 2; ++kt) {
                    const bf16x8 vf = *(const bf16x8*)&VTB[sw128(d0 + c, (half * 2 + kt) * 32 + 8 * g)];
                    oacc[dt] = MFMA(pA[kt], vf, oacc[dt]);   // V[k][d0+c] = VT[d0+c][k]
                }
            }
        }
#pragma unroll
        for (int dt = 0; dt < 4; ++dt)
#pragma unroll
            for (int r = 0; r < 4; ++r)          // O tile -> QB own rows (Q is dead)
                QB[sw64(mt + 4 * g + r, dt * 16 + c)] = f2bf(oacc[dt][r]);

        // ---- out-proj accumulate: projacc += O-rows · WpT ----
        bf16x8 oA[2];
#pragma unroll
        for (int kt = 0; kt < 2; ++kt)
            oA[kt] = *(const bf16x8*)&QB[sw64(mt + c, kt * 32 + 8 * g)];
#pragma unroll
        for (int nt4 = 0; nt4 < 4; ++nt4) {
            int n0 = nt4 * 16;
#pragma unroll
            for (int kt = 0; kt < 2; ++kt) {
                const bf16x8 wp = *(const bf16x8*)&WpT[(n0 + c) * 512 + h * 64 + kt * 32 + 8 * g];
                projacc[nt4] = MFMA(oA[kt], wp, projacc[nt4]);
            }
        }
        __syncthreads();   // barrier 2: before next head overwrites KB/VTB
    }

    // ---- epilogue: + bp, coalesced f32 stores ----
    {
        float* og = out + (size_t)b * NM * ND;
#pragma unroll
        for (int nt4 = 0; nt4 < 4; ++nt4) {
            int n0 = nt4 * 16;
            float bpv = bp[n0 + c];
#pragma unroll
            for (int r = 0; r < 4; ++r)
                og[(mt + 4 * g + r) * ND + n0 + c] = projacc[nt4][r] + bpv;
        }
    }
}

extern "C" void kernel_launch(void* const* d_in, const int* in_sizes, int n_in,
                              void* d_out, int out_size, void* d_ws, size_t ws_size,
                              hipStream_t stream) {
    const float* x     = (const float*)d_in[0];
    const int*   edges = (const int*)d_in[1];
    const float* Wq    = (const float*)d_in[2];
    const float* bq    = (const float*)d_in[3];
    const float* Wk    = (const float*)d_in[4];
    const float* bk    = (const float*)d_in[5];
    const float* Wv    = (const float*)d_in[6];
    const float* bv    = (const float*)d_in[7];
    const float* eb    = (const float*)d_in[8];
    const float* Wp    = (const float*)d_in[9];
    const float* bp    = (const float*)d_in[10];
    float* out = (float*)d_out;
    ushort_t* ws = (ushort_t*)d_ws;   // needs 262144 B

    hipLaunchKernelGGL(geat_prep, dim3(512), dim3(256), 0, stream, Wq, Wk, Wv, Wp, ws);
    hipLaunchKernelGGL(geat_mfma, dim3(NB), dim3(512), 0, stream,
                       x, edges, bq, bk, bv, eb, bp, ws, out);
}